// Round 3
// baseline (480.743 us; speedup 1.0000x reference)
//
#include <hip/hip_runtime.h>
#include <hip/hip_bf16.h>
#include <math.h>

// ---------------- problem constants ----------------
#define B_SZ   2
#define L_SZ   2048
#define DM     1024          // d_model
#define DI     2048          // d_inner
#define DS     16            // d_state
#define M_SZ   (B_SZ * L_SZ) // 4096 rows
#define N_XZ   (2 * DI)      // 4096
#define LDF    20            // uints per LDS row (32 bf16 + 8 pad) -- r8-proven
#define SEGS   4
#define SEGLEN 512           // L_SZ / SEGS
#define PSTR   68            // Ps [u][lane] padded stride (r0-proven)

typedef short bf16x8 __attribute__((ext_vector_type(8)));
typedef float f32x4  __attribute__((ext_vector_type(4)));

__device__ __forceinline__ unsigned short rne16(float f) {
  unsigned int u = __builtin_bit_cast(unsigned int, f);
  u += 0x7FFFu + ((u >> 16) & 1u);
  return (unsigned short)(u >> 16);
}
__device__ __forceinline__ float frombf(unsigned short h) {
  unsigned int u = ((unsigned int)h) << 16;
  return __builtin_bit_cast(float, u);
}

// ---------------- x -> (x_hi, x_lo) bf16 split ----------------
__global__ __launch_bounds__(256) void convert_x(
    const float* __restrict__ x, unsigned short* __restrict__ xh,
    unsigned short* __restrict__ xl) {
  int i = (blockIdx.x * 256 + threadIdx.x) * 4;
  float4 v = *(const float4*)(x + i);
  unsigned short h0 = rne16(v.x), h1 = rne16(v.y), h2 = rne16(v.z), h3 = rne16(v.w);
  *(ushort4*)(xh + i) = make_ushort4(h0, h1, h2, h3);
  *(ushort4*)(xl + i) = make_ushort4(rne16(v.x - frombf(h0)), rne16(v.y - frombf(h1)),
                                     rne16(v.z - frombf(h2)), rne16(v.w - frombf(h3)));
}

// ---------------- W (RxC fp32) -> W^T (CxR) bf16 hi (+lo) ----------------
__global__ __launch_bounds__(256) void transpose_w(
    const float* __restrict__ in, int R, int C,
    unsigned short* __restrict__ oh, unsigned short* __restrict__ ol) {
  __shared__ float T[64][65];
  const int tid = threadIdx.x;
  const int c0 = blockIdx.x * 64, r0 = blockIdx.y * 64;
  const int cc = tid & 63, rq = tid >> 6;
  #pragma unroll
  for (int i = 0; i < 16; ++i) {
    int r = rq * 16 + i;
    T[r][cc] = in[(size_t)(r0 + r) * C + c0 + cc];
  }
  __syncthreads();
  #pragma unroll
  for (int i = 0; i < 16; ++i) {
    int c = rq * 16 + i;
    float v = T[cc][c];
    size_t o = (size_t)(c0 + c) * R + r0 + cc;
    unsigned short h = rne16(v);
    oh[o] = h;
    if (ol) ol[o] = rne16(v - frombf(h));
  }
}

// ---------------- bf16 MFMA GEMM (optionally bf16x3), pre-converted inputs ----------------
// EXACT r8-proven body (LDF=20, launch_bounds (256, X3?3:4)); only the epilogue
// output path is parameterized (OUTBF16).
template<int BN, bool X3, bool OUTBF16>
__global__ __launch_bounds__(256, X3 ? 3 : 4) void gemm_t(
    const unsigned short* __restrict__ Ah, const unsigned short* __restrict__ Al, int lda,
    const unsigned short* __restrict__ Bh, const unsigned short* __restrict__ Bl, int ldb,
    const float* __restrict__ bias, float* __restrict__ Cf,
    unsigned short* __restrict__ Cz, int ldc, int K) {
  constexpr int WN  = BN / 2;      // wave col extent
  constexpr int FJ  = BN / 32;     // col frags per wave
  constexpr int BCH = BN / 64;     // B staging chunks per thread
  __shared__ unsigned int AhS[128 * LDF];
  __shared__ unsigned int BhS[BN * LDF];
  __shared__ unsigned int AlS[X3 ? 128 * LDF : 4];
  __shared__ unsigned int BlS[X3 ? BN * LDF : 4];
  const int tid  = threadIdx.x;
  const int lane = tid & 63, wave = tid >> 6;
  const int wr = wave >> 1, wc = wave & 1;
  const int lm = lane & 15, lq = lane >> 4;
  const int row0 = blockIdx.y * 128, col0 = blockIdx.x * BN;

  f32x4 acc[4][FJ];
  #pragma unroll
  for (int i = 0; i < 4; ++i)
    #pragma unroll
    for (int j = 0; j < FJ; ++j) acc[i][j] = (f32x4){0.f, 0.f, 0.f, 0.f};

  for (int k0 = 0; k0 < K; k0 += 32) {
    __syncthreads();
    // A tiles: 128 rows x 32 k, uint4 (8 bf16) per chunk
    #pragma unroll
    for (int i = 0; i < 2; ++i) {
      int idx = tid + i * 256, r = idx >> 2, q = idx & 3;
      size_t go = (size_t)(row0 + r) * lda + k0 + q * 8;
      *(uint4*)&AhS[r * LDF + q * 4] = *(const uint4*)(Ah + go);
      if constexpr (X3)
        *(uint4*)&AlS[r * LDF + q * 4] = *(const uint4*)(Al + go);
    }
    // B tiles: BN rows (n) x 32 k
    #pragma unroll
    for (int i = 0; i < BCH; ++i) {
      int idx = tid + i * 256, r = idx >> 2, q = idx & 3;
      size_t go = (size_t)(col0 + r) * ldb + k0 + q * 8;
      *(uint4*)&BhS[r * LDF + q * 4] = *(const uint4*)(Bh + go);
      if constexpr (X3)
        *(uint4*)&BlS[r * LDF + q * 4] = *(const uint4*)(Bl + go);
    }
    __syncthreads();
    bf16x8 bh[FJ], bl[FJ];
    #pragma unroll
    for (int j = 0; j < FJ; ++j) {
      bh[j] = *(const bf16x8*)&BhS[(wc * WN + j * 16 + lm) * LDF + lq * 4];
      if constexpr (X3)
        bl[j] = *(const bf16x8*)&BlS[(wc * WN + j * 16 + lm) * LDF + lq * 4];
    }
    #pragma unroll
    for (int i = 0; i < 4; ++i) {
      bf16x8 ah = *(const bf16x8*)&AhS[(wr * 64 + i * 16 + lm) * LDF + lq * 4];
      bf16x8 al;
      if constexpr (X3)
        al = *(const bf16x8*)&AlS[(wr * 64 + i * 16 + lm) * LDF + lq * 4];
      #pragma unroll
      for (int j = 0; j < FJ; ++j) {
        acc[i][j] = __builtin_amdgcn_mfma_f32_16x16x32_bf16(ah, bh[j], acc[i][j], 0, 0, 0);
        if constexpr (X3) {
          acc[i][j] = __builtin_amdgcn_mfma_f32_16x16x32_bf16(ah, bl[j], acc[i][j], 0, 0, 0);
          acc[i][j] = __builtin_amdgcn_mfma_f32_16x16x32_bf16(al, bh[j], acc[i][j], 0, 0, 0);
        }
      }
    }
  }
  // epilogue: C/D layout col=lane&15, row=(lane>>4)*4+reg
  #pragma unroll
  for (int i = 0; i < 4; ++i) {
    #pragma unroll
    for (int j = 0; j < FJ; ++j) {
      int c = col0 + wc * WN + j * 16 + lm;
      float bs = bias[c];
      #pragma unroll
      for (int k = 0; k < 4; ++k) {
        int r = row0 + wr * 64 + i * 16 + lq * 4 + k;
        float v = acc[i][j][k] + bs;
        if constexpr (OUTBF16) Cz[(size_t)r * ldc + c] = rne16(v);
        else                   Cf[(size_t)r * ldc + c] = v;
      }
    }
  }
}

// ---------------- depthwise causal conv (k=4, left pad 3) + SiLU ----------------
__global__ __launch_bounds__(256) void conv_silu_kernel(
    const float* __restrict__ xi, const float* __restrict__ Wc,
    const float* __restrict__ bc, float* __restrict__ xc) {
  int idx = blockIdx.x * blockDim.x + threadIdx.x;   // over M_SZ*DI
  if (idx >= M_SZ * DI) return;
  int d  = idx & (DI - 1);
  int bl = idx >> 11;            // row (b*L + l)
  int l  = bl & (L_SZ - 1);
  float4 w = ((const float4*)Wc)[d];
  const float* base = xi + (size_t)bl * DI + d;
  float s = bc[d] + base[0] * w.w;
  if (l >= 1) s = fmaf(base[-DI],     w.z, s);
  if (l >= 2) s = fmaf(base[-2 * DI], w.y, s);
  if (l >= 3) s = fmaf(base[-3 * DI], w.x, s);
  float sig = 1.f / (1.f + expf(-s));
  xc[idx] = s * sig;
}

// ---------------- skinny GEMM: BCm[row][s] = {xc@W_B + b_B, xc@W_C + b_C} ----------------
// Interleaved {B,C} float2 per (row, s) so the scan reads both in one b64 load.
__global__ __launch_bounds__(256) void gemm_bc_kernel(
    const float* __restrict__ xc,
    const float* __restrict__ WB, const float* __restrict__ bB,
    const float* __restrict__ WC, const float* __restrict__ bC,
    float* __restrict__ BCm) {
  int t = blockIdx.x * blockDim.x + threadIdx.x;  // M_SZ*32
  int row = t >> 5;
  int cc  = t & 31;
  int s   = cc & 15;
  const float* W = (cc < 16) ? WB : WC;
  const float4* xr4 = (const float4*)(xc + (size_t)row * DI);
  float acc = 0.f;
  #pragma unroll 4
  for (int k4 = 0; k4 < DI / 4; ++k4) {
    float4 xv = xr4[k4];
    int k = k4 * 4;
    acc = fmaf(xv.x, W[(k    ) * DS + s], acc);
    acc = fmaf(xv.y, W[(k + 1) * DS + s], acc);
    acc = fmaf(xv.z, W[(k + 2) * DS + s], acc);
    acc = fmaf(xv.w, W[(k + 3) * DS + s], acc);
  }
  if (cc < 16) BCm[row * 32 + s * 2]     = acc + bB[s];
  else         BCm[row * 32 + s * 2 + 1] = acc + bC[s];
}

// ---------------- selective scan: two-pass segmented, bitwise-exact ----------------
// r2 post-mortem: every single-pass variant is 1024 waves = 1 wave/SIMD with a
// 2048-step serial chain -> latency-bound at ~129 cyc/step regardless of
// reduce scheme. Fix = more waves. Clip nonlinearity forbids algebraic
// parallel-scan, so:
//   pass1: run the IDENTICAL serial recurrence (same mul->fmaf->min->max op
//          order, same inputs) over l=0..1535; store exact h at l=512/1024/1536.
//   pass2: 4 independent 512-step segments from those exact states (4096 waves,
//          full-chip residency at 4/SIMD) computing y + gate + store.
// Identical fp ops in identical order -> bitwise-identical output. Work x1.75,
// parallelism x4.
// Both passes: no LDS staging. x fetched once per 16 steps per lane and
// broadcast per-step via ds_swizzle (and=0x10, or=k: lane <- (lane&16)|k within
// each 32-half = 16-lane broadcast, channel-correct for dd=0..3). B/C as direct
// per-step scalar/float2 loads (16 distinct addrs, 4-way lane broadcast, 1-2
// lines per instr; L1/L2 serve the heavy cross-block reuse).

#define SWZ_BCAST16(k, xr) \
  __builtin_bit_cast(float, __builtin_amdgcn_ds_swizzle( \
      __builtin_bit_cast(int, (xr)), ((k) << 5) | 0x10))

// ---- pass 1: boundary states ----
#define P1STEP(k, xr, bb) { \
  float xk = SWZ_BCAST16(k, xr); \
  h = fmaf(h, A, xk * (bb)[k]); \
  h = fminf(fmaxf(h, -100.f), 100.f); }

#define P1WIN(xr, bb) \
  P1STEP(0, xr, bb)  P1STEP(1, xr, bb)  P1STEP(2, xr, bb)  P1STEP(3, xr, bb) \
  P1STEP(4, xr, bb)  P1STEP(5, xr, bb)  P1STEP(6, xr, bb)  P1STEP(7, xr, bb) \
  P1STEP(8, xr, bb)  P1STEP(9, xr, bb)  P1STEP(10, xr, bb) P1STEP(11, xr, bb) \
  P1STEP(12, xr, bb) P1STEP(13, xr, bb) P1STEP(14, xr, bb) P1STEP(15, xr, bb)

__global__ __launch_bounds__(256, 4) void scan_pass1(
    const float* __restrict__ xc, const float* __restrict__ BCm,
    const float* __restrict__ A_log, float* __restrict__ hseg) {
  const int b    = blockIdx.y;
  const int wave = threadIdx.x >> 6;
  const int lane = threadIdx.x & 63;
  const int dd   = lane >> 4, s = lane & 15;
  const int d    = blockIdx.x * 16 + wave * 4 + dd;

  float Alog = A_log[d * DS + s];
  Alog = fminf(fmaxf(Alog, -10.f), 2.f);
  const float A = -expf(Alog);
  float h = 0.f;

  const float* px = xc  + (size_t)b * L_SZ * DI + d;      // + s-row at load
  const float* pb = BCm + (size_t)b * L_SZ * 32 + s * 2;  // B component

  float xrA, xrB, bA[16], bB16[16];
  {
    xrA = px[s * DI];
    #pragma unroll
    for (int j = 0; j < 16; ++j) bA[j] = pb[j * 32];
  }
  for (int g = 0; g < 96; g += 2) {   // 96 windows x 16 = 1536 steps
    {
      const int t0 = (g + 1) * 16;
      xrB = px[(t0 + s) * DI];
      #pragma unroll
      for (int j = 0; j < 16; ++j) bB16[j] = pb[(t0 + j) * 32];
    }
    P1WIN(xrA, bA)
    if (g + 2 < 96) {
      const int t0 = (g + 2) * 16;
      xrA = px[(t0 + s) * DI];
      #pragma unroll
      for (int j = 0; j < 16; ++j) bA[j] = pb[(t0 + j) * 32];
    }
    P1WIN(xrB, bB16)
    if (((g + 1) & 31) == 31)
      hseg[(((size_t)b * 3 + ((g + 1) >> 5)) * DI + d) * DS + s] = h;
  }
}

// ---- pass 2: per-segment scan + y + gate + store ----
#define P2STEP(k, xr, bc) { \
  float xk = SWZ_BCAST16(k, xr); \
  h = fmaf(h, A, xk * (bc)[k].x); \
  h = fminf(fmaxf(h, -100.f), 100.f); \
  Ps[(k) * PSTR + lane] = fmaf(dsel, xk, h * (bc)[k].y); }

#define P2WIN(xr, bc) \
  P2STEP(0, xr, bc)  P2STEP(1, xr, bc)  P2STEP(2, xr, bc)  P2STEP(3, xr, bc) \
  P2STEP(4, xr, bc)  P2STEP(5, xr, bc)  P2STEP(6, xr, bc)  P2STEP(7, xr, bc) \
  P2STEP(8, xr, bc)  P2STEP(9, xr, bc)  P2STEP(10, xr, bc) P2STEP(11, xr, bc) \
  P2STEP(12, xr, bc) P2STEP(13, xr, bc) P2STEP(14, xr, bc) P2STEP(15, xr, bc)

__global__ __launch_bounds__(256, 4) void scan_pass2(
    const float* __restrict__ xc, const float* __restrict__ BCm,
    const unsigned short* __restrict__ zb,
    const float* __restrict__ A_log, const float* __restrict__ Dv,
    const float* __restrict__ hseg, unsigned short* __restrict__ yg) {
  const int b    = blockIdx.y >> 2;
  const int seg  = blockIdx.y & 3;
  const int wave = threadIdx.x >> 6;
  const int lane = threadIdx.x & 63;
  const int dd   = lane >> 4, s = lane & 15;
  const int lr   = lane >> 2, ddr = lane & 3;
  const int dw0  = blockIdx.x * 16 + wave * 4;

  __shared__ float SM[4 * (16 * PSTR + 256)];   // 21.5 KB: Ps + yS per wave
  float* Ps = SM + wave * (16 * PSTR + 256);
  float* yS = Ps + 16 * PSTR;

  float Alog = A_log[(dw0 + dd) * DS + s];
  Alog = fminf(fmaxf(Alog, -10.f), 2.f);
  const float A    = -expf(Alog);
  const float dsel = (s == 0) ? Dv[dw0 + dd] : 0.f;   // r1-proven D*x fold

  float h = 0.f;
  if (seg > 0)
    h = hseg[(((size_t)b * 3 + (seg - 1)) * DI + dw0 + dd) * DS + s];

  const int rbase = b * L_SZ + seg * SEGLEN;
  const float* px  = xc  + (size_t)rbase * DI + dw0 + dd;
  const float* pbc = BCm + (size_t)rbase * 32 + s * 2;

  float  xrA, xrB;
  float2 bcA[16], bcB[16];
  {
    xrA = px[s * DI];
    #pragma unroll
    for (int j = 0; j < 16; ++j) bcA[j] = *(const float2*)(pbc + j * 32);
  }
  for (int w = 0; w < 32; w += 2) {   // 32 windows x 16 = 512 steps
    {
      const int t0 = (w + 1) * 16;
      xrB = px[(t0 + s) * DI];
      #pragma unroll
      for (int j = 0; j < 16; ++j) bcB[j] = *(const float2*)(pbc + (t0 + j) * 32);
    }
    // ---- window w ----
    P2WIN(xrA, bcA)
    asm volatile("" ::: "memory");
    {
      const float* pp = Ps + lr * PSTR + ddr * 16;
      float4 a0 = *(const float4*)(pp + 0);
      float4 a1 = *(const float4*)(pp + 4);
      float4 a2 = *(const float4*)(pp + 8);
      float4 a3 = *(const float4*)(pp + 12);
      float t0 = (a0.x + a0.y) + (a0.z + a0.w);
      float t1 = (a1.x + a1.y) + (a1.z + a1.w);
      float t2 = (a2.x + a2.y) + (a2.z + a2.w);
      float t3 = (a3.x + a3.y) + (a3.z + a3.w);
      float y = (t0 + t1) + (t2 + t3);
      y = fminf(fmaxf(y, -100.f), 100.f);
      yS[((w & 3) * 16 + lr) * 4 + ddr] = y;
    }
    asm volatile("" ::: "memory");
    if (w + 2 < 32) {
      const int t0 = (w + 2) * 16;
      xrA = px[(t0 + s) * DI];
      #pragma unroll
      for (int j = 0; j < 16; ++j) bcA[j] = *(const float2*)(pbc + (t0 + j) * 32);
    }
    // ---- window w+1 ----
    P2WIN(xrB, bcB)
    asm volatile("" ::: "memory");
    {
      const float* pp = Ps + lr * PSTR + ddr * 16;
      float4 a0 = *(const float4*)(pp + 0);
      float4 a1 = *(const float4*)(pp + 4);
      float4 a2 = *(const float4*)(pp + 8);
      float4 a3 = *(const float4*)(pp + 12);
      float t0 = (a0.x + a0.y) + (a0.z + a0.w);
      float t1 = (a1.x + a1.y) + (a1.z + a1.w);
      float t2 = (a2.x + a2.y) + (a2.z + a2.w);
      float t3 = (a3.x + a3.y) + (a3.z + a3.w);
      float y = (t0 + t1) + (t2 + t3);
      y = fminf(fmaxf(y, -100.f), 100.f);
      yS[(((w + 1) & 3) * 16 + lr) * 4 + ddr] = y;
    }
    asm volatile("" ::: "memory");
    if (((w + 1) & 3) == 3) {   // emit 64 rows
      const int l0 = ((w + 1) - 3) * 16;
      float4 yv = *(const float4*)&yS[lane * 4];
      const int row = rbase + l0 + lane;
      uint2 zB = *(const uint2*)(zb + (size_t)row * DI + dw0);
      float zf0 = frombf((unsigned short)(zB.x & 0xFFFF));
      float zf1 = frombf((unsigned short)(zB.x >> 16));
      float zf2 = frombf((unsigned short)(zB.y & 0xFFFF));
      float zf3 = frombf((unsigned short)(zB.y >> 16));
      ushort4 o;
      o.x = rne16(yv.x * (1.f / (1.f + expf(-zf0))));
      o.y = rne16(yv.y * (1.f / (1.f + expf(-zf1))));
      o.z = rne16(yv.z * (1.f / (1.f + expf(-zf2))));
      o.w = rne16(yv.w * (1.f / (1.f + expf(-zf3))));
      *(ushort4*)(yg + (size_t)row * DI + dw0) = o;
      asm volatile("" ::: "memory");
    }
  }
}

// ---------------- launch ----------------
// ws layout (bytes), peak 88.6 MB (unchanged):
//   [0,        16777216)  yg bf16 (after conv; region was xi fp32 GEMM1 out)
//   [16777216, 17563648)  hseg fp32 (segment boundary states, 768 KB)
//   [17825792, 18350080)  BCm fp32 interleaved {B,C} (512 KB)
//   [0,        33554432)  xi fp32 before conv (GEMM1 out, conv in)
//   [33554432, 50331648)  z bf16
//   [50331648, 83886080)  xc fp32 (conv out); BEFORE conv hosts xh/xl/WhT/WlT
//   [83886080, 84410368)  (old Bm/Cm slots, unused)
//   [84410368, 88604672)  WoutT bf16
extern "C" void kernel_launch(void* const* d_in, const int* in_sizes, int n_in,
                              void* d_out, int out_size, void* d_ws, size_t ws_size,
                              hipStream_t stream) {
  const float* x      = (const float*)d_in[0];
  const float* W_in   = (const float*)d_in[1];
  const float* b_in   = (const float*)d_in[2];
  const float* W_conv = (const float*)d_in[3];
  const float* b_conv = (const float*)d_in[4];
  const float* A_log  = (const float*)d_in[5];
  const float* Dv     = (const float*)d_in[6];
  const float* W_B    = (const float*)d_in[7];
  const float* b_B    = (const float*)d_in[8];
  const float* W_C    = (const float*)d_in[9];
  const float* b_C    = (const float*)d_in[10];
  const float* W_out  = (const float*)d_in[11];
  const float* b_out  = (const float*)d_in[12];
  float* out = (float*)d_out;

  char* w = (char*)d_ws;
  float*          xi   = (float*)(w + 0);
  unsigned short* yg   = (unsigned short*)(w + 0);          // reuse after conv
  float*          hseg = (float*)(w + 16777216);            // dead xi upper half
  float*          BCm  = (float*)(w + 17825792);
  unsigned short* zb   = (unsigned short*)(w + 33554432);
  float*          xc   = (float*)(w + 50331648);
  unsigned short* xh   = (unsigned short*)(w + 50331648);   // pre-conv phase
  unsigned short* xl   = (unsigned short*)(w + 58720256);
  unsigned short* WhT  = (unsigned short*)(w + 67108864);
  unsigned short* WlT  = (unsigned short*)(w + 75497472);
  unsigned short* WoT  = (unsigned short*)(w + 84410368);

  // 0a) x -> xh/xl
  convert_x<<<M_SZ * DM / 1024, 256, 0, stream>>>(x, xh, xl);
  // 0b) W_in (DM x N_XZ) -> WhT/WlT (N_XZ x DM)
  transpose_w<<<dim3(N_XZ / 64, DM / 64), 256, 0, stream>>>(W_in, DM, N_XZ, WhT, WlT);
  // 0c) W_out (DI x DM) -> WoT (DM x DI), hi only (post-scan path)
  transpose_w<<<dim3(DM / 64, DI / 64), 256, 0, stream>>>(W_out, DI, DM, WoT, nullptr);

  // 1a) xi = x @ W_in[:, :DI] + b_in[:DI]  -- bf16x3 (scan-sensitive), fp32 out
  gemm_t<128, true, false><<<dim3(DI / 128, M_SZ / 128), 256, 0, stream>>>(
      xh, xl, DM, WhT, WlT, DM, b_in, xi, nullptr, DI, DM);

  // 1b) z = x @ W_in[:, DI:] + b_in[DI:]  -- plain bf16 (gate path), bf16 out
  gemm_t<128, false, true><<<dim3(DI / 128, M_SZ / 128), 256, 0, stream>>>(
      xh, nullptr, DM, WhT + (size_t)DI * DM, nullptr, DM,
      b_in + DI, nullptr, zb, DI, DM);

  // 2) xc = silu(causal_dwconv(xi) + b_conv)
  conv_silu_kernel<<<M_SZ * DI / 256, 256, 0, stream>>>(xi, W_conv, b_conv, xc);

  // 3) BCm interleaved projections
  gemm_bc_kernel<<<M_SZ * 32 / 256, 256, 0, stream>>>(xc, W_B, b_B, W_C, b_C, BCm);

  // 4a) pass1: serial recurrence l=0..1535, store exact boundary states
  scan_pass1<<<dim3(DI / 16, B_SZ), 256, 0, stream>>>(xc, BCm, A_log, hseg);

  // 4b) pass2: 4 parallel 512-step segments -> yg bf16 (bitwise == serial)
  scan_pass2<<<dim3(DI / 16, B_SZ * SEGS), 256, 0, stream>>>(
      xc, BCm, zb, A_log, Dv, hseg, yg);

  // 5) out = yg @ W_out + b_out, pure bf16 MFMA (BN=64)
  gemm_t<64, false, false><<<dim3(DM / 64, M_SZ / 128), 256, 0, stream>>>(
      yg, nullptr, DI, WoT, nullptr, DI, b_out, out, nullptr, DM, DI);
}

// Round 4
// 436.028 us; speedup vs baseline: 1.1025x; 1.1025x over previous
//
#include <hip/hip_runtime.h>
#include <hip/hip_bf16.h>
#include <math.h>

// ---------------- problem constants ----------------
#define B_SZ   2
#define L_SZ   2048
#define DM     1024          // d_model
#define DI     2048          // d_inner
#define DS     16            // d_state
#define M_SZ   (B_SZ * L_SZ) // 4096 rows
#define N_XZ   (2 * DI)      // 4096
#define LDF    20            // uints per LDS row (32 bf16 + 8 pad) -- r8-proven
#define SEGS   32
#define SEGLEN 64            // L_SZ / SEGS
#define NW1    124           // pass1 windows: (SEGS-1)*SEGLEN/16

typedef short bf16x8 __attribute__((ext_vector_type(8)));
typedef float f32x4  __attribute__((ext_vector_type(4)));

__device__ __forceinline__ unsigned short rne16(float f) {
  unsigned int u = __builtin_bit_cast(unsigned int, f);
  u += 0x7FFFu + ((u >> 16) & 1u);
  return (unsigned short)(u >> 16);
}
__device__ __forceinline__ float frombf(unsigned short h) {
  unsigned int u = ((unsigned int)h) << 16;
  return __builtin_bit_cast(float, u);
}

// ---------------- x -> (x_hi, x_lo) bf16 split ----------------
__global__ __launch_bounds__(256) void convert_x(
    const float* __restrict__ x, unsigned short* __restrict__ xh,
    unsigned short* __restrict__ xl) {
  int i = (blockIdx.x * 256 + threadIdx.x) * 4;
  float4 v = *(const float4*)(x + i);
  unsigned short h0 = rne16(v.x), h1 = rne16(v.y), h2 = rne16(v.z), h3 = rne16(v.w);
  *(ushort4*)(xh + i) = make_ushort4(h0, h1, h2, h3);
  *(ushort4*)(xl + i) = make_ushort4(rne16(v.x - frombf(h0)), rne16(v.y - frombf(h1)),
                                     rne16(v.z - frombf(h2)), rne16(v.w - frombf(h3)));
}

// ---------------- W (RxC fp32) -> W^T (CxR) bf16 hi (+lo) ----------------
__global__ __launch_bounds__(256) void transpose_w(
    const float* __restrict__ in, int R, int C,
    unsigned short* __restrict__ oh, unsigned short* __restrict__ ol) {
  __shared__ float T[64][65];
  const int tid = threadIdx.x;
  const int c0 = blockIdx.x * 64, r0 = blockIdx.y * 64;
  const int cc = tid & 63, rq = tid >> 6;
  #pragma unroll
  for (int i = 0; i < 16; ++i) {
    int r = rq * 16 + i;
    T[r][cc] = in[(size_t)(r0 + r) * C + c0 + cc];
  }
  __syncthreads();
  #pragma unroll
  for (int i = 0; i < 16; ++i) {
    int c = rq * 16 + i;
    float v = T[cc][c];
    size_t o = (size_t)(c0 + c) * R + r0 + cc;
    unsigned short h = rne16(v);
    oh[o] = h;
    if (ol) ol[o] = rne16(v - frombf(h));
  }
}

// ---------------- bf16 MFMA GEMM (optionally bf16x3), pre-converted inputs ----------------
// EXACT r8-proven body (LDF=20, launch_bounds (256, X3?3:4)); only the epilogue
// output path is parameterized (OUTBF16).
template<int BN, bool X3, bool OUTBF16>
__global__ __launch_bounds__(256, X3 ? 3 : 4) void gemm_t(
    const unsigned short* __restrict__ Ah, const unsigned short* __restrict__ Al, int lda,
    const unsigned short* __restrict__ Bh, const unsigned short* __restrict__ Bl, int ldb,
    const float* __restrict__ bias, float* __restrict__ Cf,
    unsigned short* __restrict__ Cz, int ldc, int K) {
  constexpr int WN  = BN / 2;      // wave col extent
  constexpr int FJ  = BN / 32;     // col frags per wave
  constexpr int BCH = BN / 64;     // B staging chunks per thread
  __shared__ unsigned int AhS[128 * LDF];
  __shared__ unsigned int BhS[BN * LDF];
  __shared__ unsigned int AlS[X3 ? 128 * LDF : 4];
  __shared__ unsigned int BlS[X3 ? BN * LDF : 4];
  const int tid  = threadIdx.x;
  const int lane = tid & 63, wave = tid >> 6;
  const int wr = wave >> 1, wc = wave & 1;
  const int lm = lane & 15, lq = lane >> 4;
  const int row0 = blockIdx.y * 128, col0 = blockIdx.x * BN;

  f32x4 acc[4][FJ];
  #pragma unroll
  for (int i = 0; i < 4; ++i)
    #pragma unroll
    for (int j = 0; j < FJ; ++j) acc[i][j] = (f32x4){0.f, 0.f, 0.f, 0.f};

  for (int k0 = 0; k0 < K; k0 += 32) {
    __syncthreads();
    // A tiles: 128 rows x 32 k, uint4 (8 bf16) per chunk
    #pragma unroll
    for (int i = 0; i < 2; ++i) {
      int idx = tid + i * 256, r = idx >> 2, q = idx & 3;
      size_t go = (size_t)(row0 + r) * lda + k0 + q * 8;
      *(uint4*)&AhS[r * LDF + q * 4] = *(const uint4*)(Ah + go);
      if constexpr (X3)
        *(uint4*)&AlS[r * LDF + q * 4] = *(const uint4*)(Al + go);
    }
    // B tiles: BN rows (n) x 32 k
    #pragma unroll
    for (int i = 0; i < BCH; ++i) {
      int idx = tid + i * 256, r = idx >> 2, q = idx & 3;
      size_t go = (size_t)(col0 + r) * ldb + k0 + q * 8;
      *(uint4*)&BhS[r * LDF + q * 4] = *(const uint4*)(Bh + go);
      if constexpr (X3)
        *(uint4*)&BlS[r * LDF + q * 4] = *(const uint4*)(Bl + go);
    }
    __syncthreads();
    bf16x8 bh[FJ], bl[FJ];
    #pragma unroll
    for (int j = 0; j < FJ; ++j) {
      bh[j] = *(const bf16x8*)&BhS[(wc * WN + j * 16 + lm) * LDF + lq * 4];
      if constexpr (X3)
        bl[j] = *(const bf16x8*)&BlS[(wc * WN + j * 16 + lm) * LDF + lq * 4];
    }
    #pragma unroll
    for (int i = 0; i < 4; ++i) {
      bf16x8 ah = *(const bf16x8*)&AhS[(wr * 64 + i * 16 + lm) * LDF + lq * 4];
      bf16x8 al;
      if constexpr (X3)
        al = *(const bf16x8*)&AlS[(wr * 64 + i * 16 + lm) * LDF + lq * 4];
      #pragma unroll
      for (int j = 0; j < FJ; ++j) {
        acc[i][j] = __builtin_amdgcn_mfma_f32_16x16x32_bf16(ah, bh[j], acc[i][j], 0, 0, 0);
        if constexpr (X3) {
          acc[i][j] = __builtin_amdgcn_mfma_f32_16x16x32_bf16(ah, bl[j], acc[i][j], 0, 0, 0);
          acc[i][j] = __builtin_amdgcn_mfma_f32_16x16x32_bf16(al, bh[j], acc[i][j], 0, 0, 0);
        }
      }
    }
  }
  // epilogue: C/D layout col=lane&15, row=(lane>>4)*4+reg
  #pragma unroll
  for (int i = 0; i < 4; ++i) {
    #pragma unroll
    for (int j = 0; j < FJ; ++j) {
      int c = col0 + wc * WN + j * 16 + lm;
      float bs = bias[c];
      #pragma unroll
      for (int k = 0; k < 4; ++k) {
        int r = row0 + wr * 64 + i * 16 + lq * 4 + k;
        float v = acc[i][j][k] + bs;
        if constexpr (OUTBF16) Cz[(size_t)r * ldc + c] = rne16(v);
        else                   Cf[(size_t)r * ldc + c] = v;
      }
    }
  }
}

// ---------------- depthwise causal conv (k=4, left pad 3) + SiLU ----------------
__global__ __launch_bounds__(256) void conv_silu_kernel(
    const float* __restrict__ xi, const float* __restrict__ Wc,
    const float* __restrict__ bc, float* __restrict__ xc) {
  int idx = blockIdx.x * blockDim.x + threadIdx.x;   // over M_SZ*DI
  if (idx >= M_SZ * DI) return;
  int d  = idx & (DI - 1);
  int bl = idx >> 11;            // row (b*L + l)
  int l  = bl & (L_SZ - 1);
  float4 w = ((const float4*)Wc)[d];
  const float* base = xi + (size_t)bl * DI + d;
  float s = bc[d] + base[0] * w.w;
  if (l >= 1) s = fmaf(base[-DI],     w.z, s);
  if (l >= 2) s = fmaf(base[-2 * DI], w.y, s);
  if (l >= 3) s = fmaf(base[-3 * DI], w.x, s);
  float sig = 1.f / (1.f + expf(-s));
  xc[idx] = s * sig;
}

// ---------------- skinny GEMM: BCm[row][s] = {xc@W_B + b_B, xc@W_C + b_C} ----------------
// Interleaved {B,C} float2 per (row, s).
__global__ __launch_bounds__(256) void gemm_bc_kernel(
    const float* __restrict__ xc,
    const float* __restrict__ WB, const float* __restrict__ bB,
    const float* __restrict__ WC, const float* __restrict__ bC,
    float* __restrict__ BCm) {
  int t = blockIdx.x * blockDim.x + threadIdx.x;  // M_SZ*32
  int row = t >> 5;
  int cc  = t & 31;
  int s   = cc & 15;
  const float* W = (cc < 16) ? WB : WC;
  const float4* xr4 = (const float4*)(xc + (size_t)row * DI);
  float acc = 0.f;
  #pragma unroll 4
  for (int k4 = 0; k4 < DI / 4; ++k4) {
    float4 xv = xr4[k4];
    int k = k4 * 4;
    acc = fmaf(xv.x, W[(k    ) * DS + s], acc);
    acc = fmaf(xv.y, W[(k + 1) * DS + s], acc);
    acc = fmaf(xv.z, W[(k + 2) * DS + s], acc);
    acc = fmaf(xv.w, W[(k + 3) * DS + s], acc);
  }
  if (cc < 16) BCm[row * 32 + s * 2]     = acc + bB[s];
  else         BCm[row * 32 + s * 2 + 1] = acc + bC[s];
}

// ---------------- selective scan: two-pass segmented, bitwise-exact, ZERO LDS ----------------
// r3 post-mortem: both passes were LDS-pipe-throughput-bound (~37 LDS ops/window
// x 16 waves/CU ~ 46-60us each; bank conflicts 0 -> op COUNT, not conflicts).
// Fix: no LDS ops at all in the scan.
//   pass1 ((d,s)-lane): x broadcast to the 16 state-lanes is done by the MEMORY
//     COALESCER (16 lanes load the same address = 1 line, free broadcast), not
//     ds_swizzle. clip via one v_med3 (fmaf->med3 chain = ~8cyc vs 12).
//   pass2 (channel-major): lane = one channel d; h[0..15], A[0..15] live in
//     registers; the s-reduction is 16 in-lane fmafs. x/z/yg coalesced across
//     lanes; B/C rows are wave-uniform (scalar-load candidates -> SMEM pipe).
//     SEGS=32 -> 2048 waves (2/SIMD).
// Exactness: both passes run the identical mul->fmaf->fmed3 sequence with
// identical A/x/B values; boundary h stored/reloaded in fp32 -> bitwise-
// identical state trajectory vs one serial pass.

__device__ __forceinline__ float clampA(float a) {
  return fminf(fmaxf(a, -10.f), 2.f);
}

// ---- pass 1: boundary states, (d,s)-lane, window-prefetched direct loads ----
__global__ __launch_bounds__(256, 1) void scan_pass1(
    const float* __restrict__ xc, const float* __restrict__ BCm,
    const float* __restrict__ A_log, float* __restrict__ hseg) {
  const int b    = blockIdx.y;
  const int wave = threadIdx.x >> 6;
  const int lane = threadIdx.x & 63;
  const int dd   = lane >> 4, s = lane & 15;
  const int d    = blockIdx.x * 16 + wave * 4 + dd;

  const float A = -expf(clampA(A_log[d * DS + s]));
  float h = 0.f;

  const float* px = xc  + (size_t)b * L_SZ * DI + d;      // same addr across 16 s-lanes
  const float* pb = BCm + (size_t)b * L_SZ * 32 + s * 2;  // B component

  float xA[16], bA[16], xB[16], bB[16];
  #pragma unroll
  for (int j = 0; j < 16; ++j) { xA[j] = px[j * DI]; bA[j] = pb[j * 32]; }

  for (int g = 0; g < NW1; g += 2) {
    {  // prefetch window g+1
      const int t0 = (g + 1) * 16;
      #pragma unroll
      for (int j = 0; j < 16; ++j) {
        xB[j] = px[(t0 + j) * DI];
        bB[j] = pb[(t0 + j) * 32];
      }
    }
    #pragma unroll
    for (int j = 0; j < 16; ++j)
      h = __builtin_amdgcn_fmed3f(fmaf(h, A, xA[j] * bA[j]), -100.f, 100.f);
    if (g + 2 < NW1) {  // prefetch window g+2
      const int t0 = (g + 2) * 16;
      #pragma unroll
      for (int j = 0; j < 16; ++j) {
        xA[j] = px[(t0 + j) * DI];
        bA[j] = pb[(t0 + j) * 32];
      }
    }
    #pragma unroll
    for (int j = 0; j < 16; ++j)
      h = __builtin_amdgcn_fmed3f(fmaf(h, A, xB[j] * bB[j]), -100.f, 100.f);
    if ((g & 3) == 2) {  // window g+1 ended a segment: k = (g+1)>>2 in 0..30
      const int k = (g + 1) >> 2;
      hseg[(((size_t)b * (SEGS - 1) + k) * DI + d) * DS + s] = h;
    }
  }
}

// ---- pass 2: channel-major, h[16]/A[16] in registers, zero cross-lane ----
__global__ __launch_bounds__(256, 2) void scan_pass2(
    const float* __restrict__ xc, const float* __restrict__ BCm,
    const unsigned short* __restrict__ zb,
    const float* __restrict__ A_log, const float* __restrict__ Dv,
    const float* __restrict__ hseg, unsigned short* __restrict__ yg) {
  const int b   = blockIdx.y >> 5;        // SEGS = 32
  const int seg = blockIdx.y & 31;
  const int d   = blockIdx.x * 256 + threadIdx.x;

  float A[16], h[16];
  #pragma unroll
  for (int q = 0; q < 4; ++q) {
    float4 al = *(const float4*)(A_log + d * DS + q * 4);
    A[q * 4 + 0] = -expf(clampA(al.x));
    A[q * 4 + 1] = -expf(clampA(al.y));
    A[q * 4 + 2] = -expf(clampA(al.z));
    A[q * 4 + 3] = -expf(clampA(al.w));
  }
  const float Dr = Dv[d];
  if (seg == 0) {
    #pragma unroll
    for (int s = 0; s < 16; ++s) h[s] = 0.f;
  } else {
    const float* hp = hseg + (((size_t)b * (SEGS - 1) + seg - 1) * DI + d) * DS;
    #pragma unroll
    for (int q = 0; q < 4; ++q) {
      float4 hv = *(const float4*)(hp + q * 4);
      h[q * 4 + 0] = hv.x; h[q * 4 + 1] = hv.y;
      h[q * 4 + 2] = hv.z; h[q * 4 + 3] = hv.w;
    }
  }

  const int rbase = b * L_SZ + seg * SEGLEN;
  const float*          px  = xc  + (size_t)rbase * DI + d;
  const unsigned short* pz  = zb  + (size_t)rbase * DI + d;
  unsigned short*       py  = yg  + (size_t)rbase * DI + d;
  const float*          pbc = BCm + (size_t)rbase * 32;

  #pragma unroll 2
  for (int t = 0; t < SEGLEN; ++t) {
    const float x = px[t * DI];
    const float* bc = pbc + t * 32;   // wave-uniform address
    float y = Dr * x;
    #pragma unroll
    for (int s = 0; s < 16; ++s) {
      h[s] = __builtin_amdgcn_fmed3f(fmaf(h[s], A[s], x * bc[s * 2]), -100.f, 100.f);
      y = fmaf(h[s], bc[s * 2 + 1], y);
    }
    y = __builtin_amdgcn_fmed3f(y, -100.f, 100.f);
    const float zf = frombf(pz[t * DI]);
    py[t * DI] = rne16(y * (1.f / (1.f + expf(-zf))));
  }
}

// ---------------- launch ----------------
// ws layout (bytes), peak 88.6 MB:
//   [0,        16777216)  yg bf16 (after conv; region was xi fp32 GEMM1 out)
//   [16777216, 24903680)  hseg fp32 (31 boundary states, 8.1 MB)
//   [25165824, 25690112)  BCm fp32 interleaved {B,C} (512 KB)
//   [0,        33554432)  xi fp32 before conv (GEMM1 out, conv in)
//   [33554432, 50331648)  z bf16
//   [50331648, 83886080)  xc fp32 (conv out); BEFORE conv hosts xh/xl/WhT/WlT
//   [84410368, 88604672)  WoutT bf16
extern "C" void kernel_launch(void* const* d_in, const int* in_sizes, int n_in,
                              void* d_out, int out_size, void* d_ws, size_t ws_size,
                              hipStream_t stream) {
  const float* x      = (const float*)d_in[0];
  const float* W_in   = (const float*)d_in[1];
  const float* b_in   = (const float*)d_in[2];
  const float* W_conv = (const float*)d_in[3];
  const float* b_conv = (const float*)d_in[4];
  const float* A_log  = (const float*)d_in[5];
  const float* Dv     = (const float*)d_in[6];
  const float* W_B    = (const float*)d_in[7];
  const float* b_B    = (const float*)d_in[8];
  const float* W_C    = (const float*)d_in[9];
  const float* b_C    = (const float*)d_in[10];
  const float* W_out  = (const float*)d_in[11];
  const float* b_out  = (const float*)d_in[12];
  float* out = (float*)d_out;

  char* w = (char*)d_ws;
  float*          xi   = (float*)(w + 0);
  unsigned short* yg   = (unsigned short*)(w + 0);          // reuse after conv
  float*          hseg = (float*)(w + 16777216);            // dead xi upper half
  float*          BCm  = (float*)(w + 25165824);
  unsigned short* zb   = (unsigned short*)(w + 33554432);
  float*          xc   = (float*)(w + 50331648);
  unsigned short* xh   = (unsigned short*)(w + 50331648);   // pre-conv phase
  unsigned short* xl   = (unsigned short*)(w + 58720256);
  unsigned short* WhT  = (unsigned short*)(w + 67108864);
  unsigned short* WlT  = (unsigned short*)(w + 75497472);
  unsigned short* WoT  = (unsigned short*)(w + 84410368);

  // 0a) x -> xh/xl
  convert_x<<<M_SZ * DM / 1024, 256, 0, stream>>>(x, xh, xl);
  // 0b) W_in (DM x N_XZ) -> WhT/WlT (N_XZ x DM)
  transpose_w<<<dim3(N_XZ / 64, DM / 64), 256, 0, stream>>>(W_in, DM, N_XZ, WhT, WlT);
  // 0c) W_out (DI x DM) -> WoT (DM x DI), hi only (post-scan path)
  transpose_w<<<dim3(DM / 64, DI / 64), 256, 0, stream>>>(W_out, DI, DM, WoT, nullptr);

  // 1a) xi = x @ W_in[:, :DI] + b_in[:DI]  -- bf16x3 (scan-sensitive), fp32 out
  gemm_t<128, true, false><<<dim3(DI / 128, M_SZ / 128), 256, 0, stream>>>(
      xh, xl, DM, WhT, WlT, DM, b_in, xi, nullptr, DI, DM);

  // 1b) z = x @ W_in[:, DI:] + b_in[DI:]  -- plain bf16 (gate path), bf16 out
  gemm_t<128, false, true><<<dim3(DI / 128, M_SZ / 128), 256, 0, stream>>>(
      xh, nullptr, DM, WhT + (size_t)DI * DM, nullptr, DM,
      b_in + DI, nullptr, zb, DI, DM);

  // 2) xc = silu(causal_dwconv(xi) + b_conv)
  conv_silu_kernel<<<M_SZ * DI / 256, 256, 0, stream>>>(xi, W_conv, b_conv, xc);

  // 3) BCm interleaved projections
  gemm_bc_kernel<<<M_SZ * 32 / 256, 256, 0, stream>>>(xc, W_B, b_B, W_C, b_C, BCm);

  // 4a) pass1: serial recurrence l=0..1983, store 31 exact boundary states
  scan_pass1<<<dim3(DI / 16, B_SZ), 256, 0, stream>>>(xc, BCm, A_log, hseg);

  // 4b) pass2: 32 parallel 64-step segments -> yg bf16 (bitwise == serial)
  scan_pass2<<<dim3(DI / 256, B_SZ * SEGS), 256, 0, stream>>>(
      xc, BCm, zb, A_log, Dv, hseg, yg);

  // 5) out = yg @ W_out + b_out, pure bf16 MFMA (BN=64)
  gemm_t<64, false, false><<<dim3(DM / 64, M_SZ / 128), 256, 0, stream>>>(
      yg, nullptr, DI, WoT, nullptr, DI, b_out, out, nullptr, DM, DI);
}

// Round 5
// 428.422 us; speedup vs baseline: 1.1221x; 1.0178x over previous
//
#include <hip/hip_runtime.h>
#include <hip/hip_bf16.h>
#include <math.h>

// ---------------- problem constants ----------------
#define B_SZ   2
#define L_SZ   2048
#define DM     1024          // d_model
#define DI     2048          // d_inner
#define DS     16            // d_state
#define M_SZ   (B_SZ * L_SZ) // 4096 rows
#define N_XZ   (2 * DI)      // 4096
#define LDF    20            // uints per LDS row (32 bf16 + 8 pad) -- r8-proven
#define SEGS   32
#define SEGLEN 64            // L_SZ / SEGS
#define SEG1   32            // pass1 register-buffer length (62 buffers over 1984 steps)

typedef short bf16x8 __attribute__((ext_vector_type(8)));
typedef float f32x4  __attribute__((ext_vector_type(4)));

__device__ __forceinline__ unsigned short rne16(float f) {
  unsigned int u = __builtin_bit_cast(unsigned int, f);
  u += 0x7FFFu + ((u >> 16) & 1u);
  return (unsigned short)(u >> 16);
}
__device__ __forceinline__ float frombf(unsigned short h) {
  unsigned int u = ((unsigned int)h) << 16;
  return __builtin_bit_cast(float, u);
}

// ---------------- x -> (x_hi, x_lo) bf16 split ----------------
__global__ __launch_bounds__(256) void convert_x(
    const float* __restrict__ x, unsigned short* __restrict__ xh,
    unsigned short* __restrict__ xl) {
  int i = (blockIdx.x * 256 + threadIdx.x) * 4;
  float4 v = *(const float4*)(x + i);
  unsigned short h0 = rne16(v.x), h1 = rne16(v.y), h2 = rne16(v.z), h3 = rne16(v.w);
  *(ushort4*)(xh + i) = make_ushort4(h0, h1, h2, h3);
  *(ushort4*)(xl + i) = make_ushort4(rne16(v.x - frombf(h0)), rne16(v.y - frombf(h1)),
                                     rne16(v.z - frombf(h2)), rne16(v.w - frombf(h3)));
}

// ---------------- W (RxC fp32) -> W^T (CxR) bf16 hi (+lo) ----------------
__global__ __launch_bounds__(256) void transpose_w(
    const float* __restrict__ in, int R, int C,
    unsigned short* __restrict__ oh, unsigned short* __restrict__ ol) {
  __shared__ float T[64][65];
  const int tid = threadIdx.x;
  const int c0 = blockIdx.x * 64, r0 = blockIdx.y * 64;
  const int cc = tid & 63, rq = tid >> 6;
  #pragma unroll
  for (int i = 0; i < 16; ++i) {
    int r = rq * 16 + i;
    T[r][cc] = in[(size_t)(r0 + r) * C + c0 + cc];
  }
  __syncthreads();
  #pragma unroll
  for (int i = 0; i < 16; ++i) {
    int c = rq * 16 + i;
    float v = T[cc][c];
    size_t o = (size_t)(c0 + c) * R + r0 + cc;
    unsigned short h = rne16(v);
    oh[o] = h;
    if (ol) ol[o] = rne16(v - frombf(h));
  }
}

// ---------------- bf16 MFMA GEMM (optionally bf16x3), pre-converted inputs ----------------
// EXACT r8-proven body (LDF=20, launch_bounds (256, X3?3:4)); only the epilogue
// output path is parameterized (OUTBF16).
template<int BN, bool X3, bool OUTBF16>
__global__ __launch_bounds__(256, X3 ? 3 : 4) void gemm_t(
    const unsigned short* __restrict__ Ah, const unsigned short* __restrict__ Al, int lda,
    const unsigned short* __restrict__ Bh, const unsigned short* __restrict__ Bl, int ldb,
    const float* __restrict__ bias, float* __restrict__ Cf,
    unsigned short* __restrict__ Cz, int ldc, int K) {
  constexpr int WN  = BN / 2;      // wave col extent
  constexpr int FJ  = BN / 32;     // col frags per wave
  constexpr int BCH = BN / 64;     // B staging chunks per thread
  __shared__ unsigned int AhS[128 * LDF];
  __shared__ unsigned int BhS[BN * LDF];
  __shared__ unsigned int AlS[X3 ? 128 * LDF : 4];
  __shared__ unsigned int BlS[X3 ? BN * LDF : 4];
  const int tid  = threadIdx.x;
  const int lane = tid & 63, wave = tid >> 6;
  const int wr = wave >> 1, wc = wave & 1;
  const int lm = lane & 15, lq = lane >> 4;
  const int row0 = blockIdx.y * 128, col0 = blockIdx.x * BN;

  f32x4 acc[4][FJ];
  #pragma unroll
  for (int i = 0; i < 4; ++i)
    #pragma unroll
    for (int j = 0; j < FJ; ++j) acc[i][j] = (f32x4){0.f, 0.f, 0.f, 0.f};

  for (int k0 = 0; k0 < K; k0 += 32) {
    __syncthreads();
    // A tiles: 128 rows x 32 k, uint4 (8 bf16) per chunk
    #pragma unroll
    for (int i = 0; i < 2; ++i) {
      int idx = tid + i * 256, r = idx >> 2, q = idx & 3;
      size_t go = (size_t)(row0 + r) * lda + k0 + q * 8;
      *(uint4*)&AhS[r * LDF + q * 4] = *(const uint4*)(Ah + go);
      if constexpr (X3)
        *(uint4*)&AlS[r * LDF + q * 4] = *(const uint4*)(Al + go);
    }
    // B tiles: BN rows (n) x 32 k
    #pragma unroll
    for (int i = 0; i < BCH; ++i) {
      int idx = tid + i * 256, r = idx >> 2, q = idx & 3;
      size_t go = (size_t)(col0 + r) * ldb + k0 + q * 8;
      *(uint4*)&BhS[r * LDF + q * 4] = *(const uint4*)(Bh + go);
      if constexpr (X3)
        *(uint4*)&BlS[r * LDF + q * 4] = *(const uint4*)(Bl + go);
    }
    __syncthreads();
    bf16x8 bh[FJ], bl[FJ];
    #pragma unroll
    for (int j = 0; j < FJ; ++j) {
      bh[j] = *(const bf16x8*)&BhS[(wc * WN + j * 16 + lm) * LDF + lq * 4];
      if constexpr (X3)
        bl[j] = *(const bf16x8*)&BlS[(wc * WN + j * 16 + lm) * LDF + lq * 4];
    }
    #pragma unroll
    for (int i = 0; i < 4; ++i) {
      bf16x8 ah = *(const bf16x8*)&AhS[(wr * 64 + i * 16 + lm) * LDF + lq * 4];
      bf16x8 al;
      if constexpr (X3)
        al = *(const bf16x8*)&AlS[(wr * 64 + i * 16 + lm) * LDF + lq * 4];
      #pragma unroll
      for (int j = 0; j < FJ; ++j) {
        acc[i][j] = __builtin_amdgcn_mfma_f32_16x16x32_bf16(ah, bh[j], acc[i][j], 0, 0, 0);
        if constexpr (X3) {
          acc[i][j] = __builtin_amdgcn_mfma_f32_16x16x32_bf16(ah, bl[j], acc[i][j], 0, 0, 0);
          acc[i][j] = __builtin_amdgcn_mfma_f32_16x16x32_bf16(al, bh[j], acc[i][j], 0, 0, 0);
        }
      }
    }
  }
  // epilogue: C/D layout col=lane&15, row=(lane>>4)*4+reg
  #pragma unroll
  for (int i = 0; i < 4; ++i) {
    #pragma unroll
    for (int j = 0; j < FJ; ++j) {
      int c = col0 + wc * WN + j * 16 + lm;
      float bs = bias[c];
      #pragma unroll
      for (int k = 0; k < 4; ++k) {
        int r = row0 + wr * 64 + i * 16 + lq * 4 + k;
        float v = acc[i][j][k] + bs;
        if constexpr (OUTBF16) Cz[(size_t)r * ldc + c] = rne16(v);
        else                   Cf[(size_t)r * ldc + c] = v;
      }
    }
  }
}

// ---------------- depthwise causal conv (k=4, left pad 3) + SiLU ----------------
__global__ __launch_bounds__(256) void conv_silu_kernel(
    const float* __restrict__ xi, const float* __restrict__ Wc,
    const float* __restrict__ bc, float* __restrict__ xc) {
  int idx = blockIdx.x * blockDim.x + threadIdx.x;   // over M_SZ*DI
  if (idx >= M_SZ * DI) return;
  int d  = idx & (DI - 1);
  int bl = idx >> 11;            // row (b*L + l)
  int l  = bl & (L_SZ - 1);
  float4 w = ((const float4*)Wc)[d];
  const float* base = xi + (size_t)bl * DI + d;
  float s = bc[d] + base[0] * w.w;
  if (l >= 1) s = fmaf(base[-DI],     w.z, s);
  if (l >= 2) s = fmaf(base[-2 * DI], w.y, s);
  if (l >= 3) s = fmaf(base[-3 * DI], w.x, s);
  float sig = 1.f / (1.f + expf(-s));
  xc[idx] = s * sig;
}

// ---------------- skinny GEMM: BCm interleaved {B,C}; Bp2 = paired-B for pass1 ----------------
// BCm[row*32 + s*2 + {0,1}] = {B,C}   (pass2 reads both in one b64)
// Bp2[(row>>1)*32 + s*2 + (row&1)]    (pass1 reads TWO timesteps per b64 ->
//                                      halves pass1's load count: 48/segment <= vmcnt 63)
__global__ __launch_bounds__(256) void gemm_bc_kernel(
    const float* __restrict__ xc,
    const float* __restrict__ WB, const float* __restrict__ bB,
    const float* __restrict__ WC, const float* __restrict__ bC,
    float* __restrict__ BCm, float* __restrict__ Bp2) {
  int t = blockIdx.x * blockDim.x + threadIdx.x;  // M_SZ*32
  int row = t >> 5;
  int cc  = t & 31;
  int s   = cc & 15;
  const float* W = (cc < 16) ? WB : WC;
  const float4* xr4 = (const float4*)(xc + (size_t)row * DI);
  float acc = 0.f;
  #pragma unroll 4
  for (int k4 = 0; k4 < DI / 4; ++k4) {
    float4 xv = xr4[k4];
    int k = k4 * 4;
    acc = fmaf(xv.x, W[(k    ) * DS + s], acc);
    acc = fmaf(xv.y, W[(k + 1) * DS + s], acc);
    acc = fmaf(xv.z, W[(k + 2) * DS + s], acc);
    acc = fmaf(xv.w, W[(k + 3) * DS + s], acc);
  }
  if (cc < 16) {
    float v = acc + bB[s];
    BCm[row * 32 + s * 2] = v;
    Bp2[(size_t)(row >> 1) * 32 + s * 2 + (row & 1)] = v;
  } else {
    BCm[row * 32 + s * 2 + 1] = acc + bC[s];
  }
}

// ---------------- selective scan: two-pass segmented, bitwise-exact, ZERO LDS ----------------
// r4 post-mortem: pass1 = 80us at 96 cyc/step -- HBM-latency-bound at 1 wave/SIMD
// (FETCH 33.8MB = all misses, ~900cyc; prefetch depth was 1x16-step window ~350cyc).
// No TLP exists (1024 waves structural), so the fix is ILP depth -- bounded by the
// hardware vmcnt limit of 63 outstanding loads (beyond it the compiler clamps to
// vmcnt(63) and force-drains fresh prefetches). r5 pass1:
//   * 32-step register buffers, double-buffered (ping-pong, full static unroll)
//   * per segment: 32 x-dword loads + 16 Bp2-float2 loads = 48 outstanding <= 63
//   * pointer-bump addressing (no per-load 64b address rebuild)
// pass2 unchanged (channel-major, h[16]/A[16] in regs, zero cross-lane, ~2/SIMD).
// Exactness: identical mul->fmaf->fmed3 sequence, identical values; boundary h
// stored/reloaded fp32 -> state trajectory identical to one serial pass.

__device__ __forceinline__ float clampA(float a) {
  return fminf(fmaxf(a, -10.f), 2.f);
}

// ---- pass 1: boundary states, (d,s)-lane, deep register pipeline ----
__global__ __launch_bounds__(256, 1) void scan_pass1(
    const float* __restrict__ xc, const float* __restrict__ Bp2,
    const float* __restrict__ A_log, float* __restrict__ hseg) {
  const int b    = blockIdx.y;
  const int wave = threadIdx.x >> 6;
  const int lane = threadIdx.x & 63;
  const int dd   = lane >> 4, s = lane & 15;
  const int d    = blockIdx.x * 16 + wave * 4 + dd;

  const float A = -expf(clampA(A_log[d * DS + s]));
  float h = 0.f;

  const float* px = xc  + (size_t)b * L_SZ * DI + d;            // x: same addr across 16 s-lanes
  const float* pb = Bp2 + (size_t)b * (L_SZ / 2) * 32 + s * 2;  // paired B

  float  x0[SEG1], x1[SEG1];
  float2 b0[SEG1 / 2], b1[SEG1 / 2];

  // prologue: buffer 0
  #pragma unroll
  for (int j = 0; j < SEG1; ++j) x0[j] = px[j * DI];
  #pragma unroll
  for (int j = 0; j < SEG1 / 2; ++j) b0[j] = *(const float2*)(pb + j * 32);
  px += SEG1 * DI; pb += (SEG1 / 2) * 32;

  // 62 buffers of 32 steps = 1984 steps; boundary store every 2 buffers (64 steps)
  for (int w = 0; w < 60; w += 2) {
    // prefetch buffer w+1
    #pragma unroll
    for (int j = 0; j < SEG1; ++j) x1[j] = px[j * DI];
    #pragma unroll
    for (int j = 0; j < SEG1 / 2; ++j) b1[j] = *(const float2*)(pb + j * 32);
    px += SEG1 * DI; pb += (SEG1 / 2) * 32;
    // compute buffer w
    #pragma unroll
    for (int j = 0; j < SEG1; ++j) {
      float bj = (j & 1) ? b0[j >> 1].y : b0[j >> 1].x;
      h = __builtin_amdgcn_fmed3f(fmaf(h, A, x0[j] * bj), -100.f, 100.f);
    }
    // prefetch buffer w+2
    #pragma unroll
    for (int j = 0; j < SEG1; ++j) x0[j] = px[j * DI];
    #pragma unroll
    for (int j = 0; j < SEG1 / 2; ++j) b0[j] = *(const float2*)(pb + j * 32);
    px += SEG1 * DI; pb += (SEG1 / 2) * 32;
    // compute buffer w+1
    #pragma unroll
    for (int j = 0; j < SEG1; ++j) {
      float bj = (j & 1) ? b1[j >> 1].y : b1[j >> 1].x;
      h = __builtin_amdgcn_fmed3f(fmaf(h, A, x1[j] * bj), -100.f, 100.f);
    }
    hseg[(((size_t)b * (SEGS - 1) + (w >> 1)) * DI + d) * DS + s] = h;
  }
  // epilogue: buffers 60 (in buf0), 61 (load now); boundary 30
  #pragma unroll
  for (int j = 0; j < SEG1; ++j) x1[j] = px[j * DI];
  #pragma unroll
  for (int j = 0; j < SEG1 / 2; ++j) b1[j] = *(const float2*)(pb + j * 32);
  #pragma unroll
  for (int j = 0; j < SEG1; ++j) {
    float bj = (j & 1) ? b0[j >> 1].y : b0[j >> 1].x;
    h = __builtin_amdgcn_fmed3f(fmaf(h, A, x0[j] * bj), -100.f, 100.f);
  }
  #pragma unroll
  for (int j = 0; j < SEG1; ++j) {
    float bj = (j & 1) ? b1[j >> 1].y : b1[j >> 1].x;
    h = __builtin_amdgcn_fmed3f(fmaf(h, A, x1[j] * bj), -100.f, 100.f);
  }
  hseg[(((size_t)b * (SEGS - 1) + 30) * DI + d) * DS + s] = h;
}

// ---- pass 2: channel-major, h[16]/A[16] in registers, zero cross-lane ----
__global__ __launch_bounds__(256, 2) void scan_pass2(
    const float* __restrict__ xc, const float* __restrict__ BCm,
    const unsigned short* __restrict__ zb,
    const float* __restrict__ A_log, const float* __restrict__ Dv,
    const float* __restrict__ hseg, unsigned short* __restrict__ yg) {
  const int b   = blockIdx.y >> 5;        // SEGS = 32
  const int seg = blockIdx.y & 31;
  const int d   = blockIdx.x * 256 + threadIdx.x;

  float A[16], h[16];
  #pragma unroll
  for (int q = 0; q < 4; ++q) {
    float4 al = *(const float4*)(A_log + d * DS + q * 4);
    A[q * 4 + 0] = -expf(clampA(al.x));
    A[q * 4 + 1] = -expf(clampA(al.y));
    A[q * 4 + 2] = -expf(clampA(al.z));
    A[q * 4 + 3] = -expf(clampA(al.w));
  }
  const float Dr = Dv[d];
  if (seg == 0) {
    #pragma unroll
    for (int s = 0; s < 16; ++s) h[s] = 0.f;
  } else {
    const float* hp = hseg + (((size_t)b * (SEGS - 1) + seg - 1) * DI + d) * DS;
    #pragma unroll
    for (int q = 0; q < 4; ++q) {
      float4 hv = *(const float4*)(hp + q * 4);
      h[q * 4 + 0] = hv.x; h[q * 4 + 1] = hv.y;
      h[q * 4 + 2] = hv.z; h[q * 4 + 3] = hv.w;
    }
  }

  const int rbase = b * L_SZ + seg * SEGLEN;
  const float*          px  = xc  + (size_t)rbase * DI + d;
  const unsigned short* pz  = zb  + (size_t)rbase * DI + d;
  unsigned short*       py  = yg  + (size_t)rbase * DI + d;
  const float*          pbc = BCm + (size_t)rbase * 32;

  #pragma unroll 2
  for (int t = 0; t < SEGLEN; ++t) {
    const float x = px[t * DI];
    const float* bc = pbc + t * 32;   // wave-uniform address
    float y = Dr * x;
    #pragma unroll
    for (int s = 0; s < 16; ++s) {
      h[s] = __builtin_amdgcn_fmed3f(fmaf(h[s], A[s], x * bc[s * 2]), -100.f, 100.f);
      y = fmaf(h[s], bc[s * 2 + 1], y);
    }
    y = __builtin_amdgcn_fmed3f(y, -100.f, 100.f);
    const float zf = frombf(pz[t * DI]);
    py[t * DI] = rne16(y * (1.f / (1.f + expf(-zf))));
  }
}

// ---------------- launch ----------------
// ws layout (bytes), peak 88.6 MB:
//   [0,        16777216)  yg bf16 (after conv; region was xi fp32 GEMM1 out)
//   [16777216, 24903680)  hseg fp32 (31 boundary states, 8.1 MB)
//   [25165824, 25690112)  BCm fp32 interleaved {B,C} (512 KB)
//   [25690112, 25952256)  Bp2 fp32 paired-B (256 KB)
//   [0,        33554432)  xi fp32 before conv (GEMM1 out, conv in)
//   [33554432, 50331648)  z bf16
//   [50331648, 83886080)  xc fp32 (conv out); BEFORE conv hosts xh/xl/WhT/WlT
//   [84410368, 88604672)  WoutT bf16
extern "C" void kernel_launch(void* const* d_in, const int* in_sizes, int n_in,
                              void* d_out, int out_size, void* d_ws, size_t ws_size,
                              hipStream_t stream) {
  const float* x      = (const float*)d_in[0];
  const float* W_in   = (const float*)d_in[1];
  const float* b_in   = (const float*)d_in[2];
  const float* W_conv = (const float*)d_in[3];
  const float* b_conv = (const float*)d_in[4];
  const float* A_log  = (const float*)d_in[5];
  const float* Dv     = (const float*)d_in[6];
  const float* W_B    = (const float*)d_in[7];
  const float* b_B    = (const float*)d_in[8];
  const float* W_C    = (const float*)d_in[9];
  const float* b_C    = (const float*)d_in[10];
  const float* W_out  = (const float*)d_in[11];
  const float* b_out  = (const float*)d_in[12];
  float* out = (float*)d_out;

  char* w = (char*)d_ws;
  float*          xi   = (float*)(w + 0);
  unsigned short* yg   = (unsigned short*)(w + 0);          // reuse after conv
  float*          hseg = (float*)(w + 16777216);            // dead xi upper half
  float*          BCm  = (float*)(w + 25165824);
  float*          Bp2  = (float*)(w + 25690112);
  unsigned short* zb   = (unsigned short*)(w + 33554432);
  float*          xc   = (float*)(w + 50331648);
  unsigned short* xh   = (unsigned short*)(w + 50331648);   // pre-conv phase
  unsigned short* xl   = (unsigned short*)(w + 58720256);
  unsigned short* WhT  = (unsigned short*)(w + 67108864);
  unsigned short* WlT  = (unsigned short*)(w + 75497472);
  unsigned short* WoT  = (unsigned short*)(w + 84410368);

  // 0a) x -> xh/xl
  convert_x<<<M_SZ * DM / 1024, 256, 0, stream>>>(x, xh, xl);
  // 0b) W_in (DM x N_XZ) -> WhT/WlT (N_XZ x DM)
  transpose_w<<<dim3(N_XZ / 64, DM / 64), 256, 0, stream>>>(W_in, DM, N_XZ, WhT, WlT);
  // 0c) W_out (DI x DM) -> WoT (DM x DI), hi only (post-scan path)
  transpose_w<<<dim3(DM / 64, DI / 64), 256, 0, stream>>>(W_out, DI, DM, WoT, nullptr);

  // 1a) xi = x @ W_in[:, :DI] + b_in[:DI]  -- bf16x3 (scan-sensitive), fp32 out
  gemm_t<128, true, false><<<dim3(DI / 128, M_SZ / 128), 256, 0, stream>>>(
      xh, xl, DM, WhT, WlT, DM, b_in, xi, nullptr, DI, DM);

  // 1b) z = x @ W_in[:, DI:] + b_in[DI:]  -- plain bf16 (gate path), bf16 out
  gemm_t<128, false, true><<<dim3(DI / 128, M_SZ / 128), 256, 0, stream>>>(
      xh, nullptr, DM, WhT + (size_t)DI * DM, nullptr, DM,
      b_in + DI, nullptr, zb, DI, DM);

  // 2) xc = silu(causal_dwconv(xi) + b_conv)
  conv_silu_kernel<<<M_SZ * DI / 256, 256, 0, stream>>>(xi, W_conv, b_conv, xc);

  // 3) BCm interleaved projections + Bp2 paired-B copy
  gemm_bc_kernel<<<M_SZ * 32 / 256, 256, 0, stream>>>(xc, W_B, b_B, W_C, b_C, BCm, Bp2);

  // 4a) pass1: serial recurrence l=0..1983, deep register pipeline, 31 boundaries
  scan_pass1<<<dim3(DI / 16, B_SZ), 256, 0, stream>>>(xc, Bp2, A_log, hseg);

  // 4b) pass2: 32 parallel 64-step segments -> yg bf16 (bitwise == serial)
  scan_pass2<<<dim3(DI / 256, B_SZ * SEGS), 256, 0, stream>>>(
      xc, BCm, zb, A_log, Dv, hseg, yg);

  // 5) out = yg @ W_out + b_out, pure bf16 MFMA (BN=64)
  gemm_t<64, false, false><<<dim3(DM / 64, M_SZ / 128), 256, 0, stream>>>(
      yg, nullptr, DI, WoT, nullptr, DI, b_out, out, nullptr, DM, DI);
}

// Round 6
// 393.073 us; speedup vs baseline: 1.2230x; 1.0899x over previous
//
#include <hip/hip_runtime.h>
#include <hip/hip_bf16.h>
#include <math.h>

// ---------------- problem constants ----------------
#define B_SZ   2
#define L_SZ   2048
#define DM     1024          // d_model
#define DI     2048          // d_inner
#define DS     16            // d_state
#define M_SZ   (B_SZ * L_SZ) // 4096 rows
#define N_XZ   (2 * DI)      // 4096
#define LDF    20            // uints per LDS row (32 bf16 + 8 pad) -- r8-proven
#define SEGS   32
#define SEGLEN 64            // L_SZ / SEGS
#define SEG1   32            // pass1 register-buffer length
#define KZN    8             // gemm_bcf K-split factor

typedef short bf16x8 __attribute__((ext_vector_type(8)));
typedef float f32x4  __attribute__((ext_vector_type(4)));

__device__ __forceinline__ unsigned short rne16(float f) {
  unsigned int u = __builtin_bit_cast(unsigned int, f);
  u += 0x7FFFu + ((u >> 16) & 1u);
  return (unsigned short)(u >> 16);
}
__device__ __forceinline__ float frombf(unsigned short h) {
  unsigned int u = ((unsigned int)h) << 16;
  return __builtin_bit_cast(float, u);
}

// ---------------- x -> (x_hi, x_lo) bf16 split ----------------
__global__ __launch_bounds__(256) void convert_x(
    const float* __restrict__ x, unsigned short* __restrict__ xh,
    unsigned short* __restrict__ xl) {
  int i = (blockIdx.x * 256 + threadIdx.x) * 4;
  float4 v = *(const float4*)(x + i);
  unsigned short h0 = rne16(v.x), h1 = rne16(v.y), h2 = rne16(v.z), h3 = rne16(v.w);
  *(ushort4*)(xh + i) = make_ushort4(h0, h1, h2, h3);
  *(ushort4*)(xl + i) = make_ushort4(rne16(v.x - frombf(h0)), rne16(v.y - frombf(h1)),
                                     rne16(v.z - frombf(h2)), rne16(v.w - frombf(h3)));
}

// ---------------- W (RxC fp32) -> W^T (CxR) bf16 hi (+lo) ----------------
__global__ __launch_bounds__(256) void transpose_w(
    const float* __restrict__ in, int R, int C,
    unsigned short* __restrict__ oh, unsigned short* __restrict__ ol) {
  __shared__ float T[64][65];
  const int tid = threadIdx.x;
  const int c0 = blockIdx.x * 64, r0 = blockIdx.y * 64;
  const int cc = tid & 63, rq = tid >> 6;
  #pragma unroll
  for (int i = 0; i < 16; ++i) {
    int r = rq * 16 + i;
    T[r][cc] = in[(size_t)(r0 + r) * C + c0 + cc];
  }
  __syncthreads();
  #pragma unroll
  for (int i = 0; i < 16; ++i) {
    int c = rq * 16 + i;
    float v = T[cc][c];
    size_t o = (size_t)(c0 + c) * R + r0 + cc;
    unsigned short h = rne16(v);
    oh[o] = h;
    if (ol) ol[o] = rne16(v - frombf(h));
  }
}

// ---------------- bf16 MFMA GEMM (optionally bf16x3), pre-converted inputs ----------------
// EXACT r8-proven body (LDF=20, launch_bounds (256, X3?3:4)); only the epilogue
// output path is parameterized (OUTBF16).
template<int BN, bool X3, bool OUTBF16>
__global__ __launch_bounds__(256, X3 ? 3 : 4) void gemm_t(
    const unsigned short* __restrict__ Ah, const unsigned short* __restrict__ Al, int lda,
    const unsigned short* __restrict__ Bh, const unsigned short* __restrict__ Bl, int ldb,
    const float* __restrict__ bias, float* __restrict__ Cf,
    unsigned short* __restrict__ Cz, int ldc, int K) {
  constexpr int WN  = BN / 2;      // wave col extent
  constexpr int FJ  = BN / 32;     // col frags per wave
  constexpr int BCH = BN / 64;     // B staging chunks per thread
  __shared__ unsigned int AhS[128 * LDF];
  __shared__ unsigned int BhS[BN * LDF];
  __shared__ unsigned int AlS[X3 ? 128 * LDF : 4];
  __shared__ unsigned int BlS[X3 ? BN * LDF : 4];
  const int tid  = threadIdx.x;
  const int lane = tid & 63, wave = tid >> 6;
  const int wr = wave >> 1, wc = wave & 1;
  const int lm = lane & 15, lq = lane >> 4;
  const int row0 = blockIdx.y * 128, col0 = blockIdx.x * BN;

  f32x4 acc[4][FJ];
  #pragma unroll
  for (int i = 0; i < 4; ++i)
    #pragma unroll
    for (int j = 0; j < FJ; ++j) acc[i][j] = (f32x4){0.f, 0.f, 0.f, 0.f};

  for (int k0 = 0; k0 < K; k0 += 32) {
    __syncthreads();
    // A tiles: 128 rows x 32 k, uint4 (8 bf16) per chunk
    #pragma unroll
    for (int i = 0; i < 2; ++i) {
      int idx = tid + i * 256, r = idx >> 2, q = idx & 3;
      size_t go = (size_t)(row0 + r) * lda + k0 + q * 8;
      *(uint4*)&AhS[r * LDF + q * 4] = *(const uint4*)(Ah + go);
      if constexpr (X3)
        *(uint4*)&AlS[r * LDF + q * 4] = *(const uint4*)(Al + go);
    }
    // B tiles: BN rows (n) x 32 k
    #pragma unroll
    for (int i = 0; i < BCH; ++i) {
      int idx = tid + i * 256, r = idx >> 2, q = idx & 3;
      size_t go = (size_t)(col0 + r) * ldb + k0 + q * 8;
      *(uint4*)&BhS[r * LDF + q * 4] = *(const uint4*)(Bh + go);
      if constexpr (X3)
        *(uint4*)&BlS[r * LDF + q * 4] = *(const uint4*)(Bl + go);
    }
    __syncthreads();
    bf16x8 bh[FJ], bl[FJ];
    #pragma unroll
    for (int j = 0; j < FJ; ++j) {
      bh[j] = *(const bf16x8*)&BhS[(wc * WN + j * 16 + lm) * LDF + lq * 4];
      if constexpr (X3)
        bl[j] = *(const bf16x8*)&BlS[(wc * WN + j * 16 + lm) * LDF + lq * 4];
    }
    #pragma unroll
    for (int i = 0; i < 4; ++i) {
      bf16x8 ah = *(const bf16x8*)&AhS[(wr * 64 + i * 16 + lm) * LDF + lq * 4];
      bf16x8 al;
      if constexpr (X3)
        al = *(const bf16x8*)&AlS[(wr * 64 + i * 16 + lm) * LDF + lq * 4];
      #pragma unroll
      for (int j = 0; j < FJ; ++j) {
        acc[i][j] = __builtin_amdgcn_mfma_f32_16x16x32_bf16(ah, bh[j], acc[i][j], 0, 0, 0);
        if constexpr (X3) {
          acc[i][j] = __builtin_amdgcn_mfma_f32_16x16x32_bf16(ah, bl[j], acc[i][j], 0, 0, 0);
          acc[i][j] = __builtin_amdgcn_mfma_f32_16x16x32_bf16(al, bh[j], acc[i][j], 0, 0, 0);
        }
      }
    }
  }
  // epilogue: C/D layout col=lane&15, row=(lane>>4)*4+reg
  #pragma unroll
  for (int i = 0; i < 4; ++i) {
    #pragma unroll
    for (int j = 0; j < FJ; ++j) {
      int c = col0 + wc * WN + j * 16 + lm;
      float bs = bias[c];
      #pragma unroll
      for (int k = 0; k < 4; ++k) {
        int r = row0 + wr * 64 + i * 16 + lq * 4 + k;
        float v = acc[i][j][k] + bs;
        if constexpr (OUTBF16) Cz[(size_t)r * ldc + c] = rne16(v);
        else                   Cf[(size_t)r * ldc + c] = v;
      }
    }
  }
}

// ---------------- depthwise causal conv (k=4, left pad 3) + SiLU ----------------
__global__ __launch_bounds__(256) void conv_silu_kernel(
    const float* __restrict__ xi, const float* __restrict__ Wc,
    const float* __restrict__ bc, float* __restrict__ xc) {
  int idx = blockIdx.x * blockDim.x + threadIdx.x;   // over M_SZ*DI
  if (idx >= M_SZ * DI) return;
  int d  = idx & (DI - 1);
  int bl = idx >> 11;            // row (b*L + l)
  int l  = bl & (L_SZ - 1);
  float4 w = ((const float4*)Wc)[d];
  const float* base = xi + (size_t)bl * DI + d;
  float s = bc[d] + base[0] * w.w;
  if (l >= 1) s = fmaf(base[-DI],     w.z, s);
  if (l >= 2) s = fmaf(base[-2 * DI], w.y, s);
  if (l >= 3) s = fmaf(base[-3 * DI], w.x, s);
  float sig = 1.f / (1.f + expf(-s));
  xc[idx] = s * sig;
}

// ---------------- W_B/W_C -> WbcT[64][2048] bf16 hi/lo (interleaved cols, zero-padded) ----------------
// col c<32: c=(s<<1)|sel -> (sel?W_C:W_B)[k][s]; cols 32..63 zero.
__global__ __launch_bounds__(256) void prep_wbc(
    const float* __restrict__ WB, const float* __restrict__ WC,
    unsigned short* __restrict__ Wh, unsigned short* __restrict__ Wl) {
  int idx = blockIdx.x * 256 + threadIdx.x;   // 64*2048
  int c = idx >> 11, k = idx & 2047;
  float v = 0.f;
  if (c < 32) {
    const float* W = (c & 1) ? WC : WB;
    v = W[k * DS + (c >> 1)];
  }
  unsigned short h = rne16(v);
  Wh[idx] = h;
  Wl[idx] = rne16(v - frombf(h));
}

// ---------------- MFMA B/C projection: parts[kz] = xc[:,kz*256:+256] @ WbcT^T ----------------
// r5 post-mortem: the VALU gemm_bc was 71us (13-20x off roofline): 2560 dependent
// VMEM ops/thread feeding ONE serial accumulator -> latency-exposed. This is the
// r8-proven gemm_t body (BN=64, X3) with two deltas:
//   * A staged from fp32 xc with on-the-fly hi/lo bf16 split (no 33.5MB converts)
//   * K-split 8x across blockIdx.x (grid 8x32 = 256 blocks = full chip; one
//     BN=64 tile alone would be 32 blocks = 1 block/CU, staging latency exposed)
// Partials summed (+bias, +Bp2 extraction) by prep_bc_sum. B/C become
// bf16x3-accurate (~2^-17 rel) -- same treatment xi already gets, and xc (their
// source) is already downstream of bf16x3; clips are continuous.
__global__ __launch_bounds__(256, 3) void gemm_bcf(
    const float* __restrict__ Af, int lda,
    const unsigned short* __restrict__ Bh, const unsigned short* __restrict__ Bl, int ldb,
    float* __restrict__ parts, int ldc, int Kslice) {
  __shared__ unsigned int AhS[128 * LDF];
  __shared__ unsigned int AlS[128 * LDF];
  __shared__ unsigned int BhS[64 * LDF];
  __shared__ unsigned int BlS[64 * LDF];
  const int tid  = threadIdx.x;
  const int lane = tid & 63, wave = tid >> 6;
  const int wr = wave >> 1, wc = wave & 1;
  const int lm = lane & 15, lq = lane >> 4;
  const int row0 = blockIdx.y * 128;
  const int kbase = blockIdx.x * Kslice;
  float* Cp = parts + (size_t)blockIdx.x * M_SZ * 64;

  f32x4 acc[4][2];
  #pragma unroll
  for (int i = 0; i < 4; ++i)
    #pragma unroll
    for (int j = 0; j < 2; ++j) acc[i][j] = (f32x4){0.f, 0.f, 0.f, 0.f};

  for (int k0 = kbase; k0 < kbase + Kslice; k0 += 32) {
    __syncthreads();
    // A: 128 rows x 32 k fp32 -> hi/lo bf16 in LDS
    #pragma unroll
    for (int i = 0; i < 4; ++i) {
      int idx = tid + i * 256, r = idx >> 3, q = idx & 7;
      float4 v = *(const float4*)(Af + (size_t)(row0 + r) * lda + k0 + q * 4);
      unsigned short h0 = rne16(v.x), h1 = rne16(v.y), h2 = rne16(v.z), h3 = rne16(v.w);
      AhS[r * LDF + q * 2]     = (unsigned)h0 | ((unsigned)h1 << 16);
      AhS[r * LDF + q * 2 + 1] = (unsigned)h2 | ((unsigned)h3 << 16);
      unsigned short l0 = rne16(v.x - frombf(h0)), l1 = rne16(v.y - frombf(h1));
      unsigned short l2 = rne16(v.z - frombf(h2)), l3 = rne16(v.w - frombf(h3));
      AlS[r * LDF + q * 2]     = (unsigned)l0 | ((unsigned)l1 << 16);
      AlS[r * LDF + q * 2 + 1] = (unsigned)l2 | ((unsigned)l3 << 16);
    }
    // B: 64 rows x 32 k bf16 (hi+lo), 256 threads = 64 rows x 4 quads
    {
      int r = tid >> 2, q = tid & 3;
      size_t go = (size_t)r * ldb + k0 + q * 8;
      *(uint4*)&BhS[r * LDF + q * 4] = *(const uint4*)(Bh + go);
      *(uint4*)&BlS[r * LDF + q * 4] = *(const uint4*)(Bl + go);
    }
    __syncthreads();
    bf16x8 bh[2], bl[2];
    #pragma unroll
    for (int j = 0; j < 2; ++j) {
      bh[j] = *(const bf16x8*)&BhS[(wc * 32 + j * 16 + lm) * LDF + lq * 4];
      bl[j] = *(const bf16x8*)&BlS[(wc * 32 + j * 16 + lm) * LDF + lq * 4];
    }
    #pragma unroll
    for (int i = 0; i < 4; ++i) {
      bf16x8 ah = *(const bf16x8*)&AhS[(wr * 64 + i * 16 + lm) * LDF + lq * 4];
      bf16x8 al = *(const bf16x8*)&AlS[(wr * 64 + i * 16 + lm) * LDF + lq * 4];
      #pragma unroll
      for (int j = 0; j < 2; ++j) {
        acc[i][j] = __builtin_amdgcn_mfma_f32_16x16x32_bf16(ah, bh[j], acc[i][j], 0, 0, 0);
        acc[i][j] = __builtin_amdgcn_mfma_f32_16x16x32_bf16(ah, bl[j], acc[i][j], 0, 0, 0);
        acc[i][j] = __builtin_amdgcn_mfma_f32_16x16x32_bf16(al, bh[j], acc[i][j], 0, 0, 0);
      }
    }
  }
  // epilogue: raw partials, no bias
  #pragma unroll
  for (int i = 0; i < 4; ++i) {
    #pragma unroll
    for (int j = 0; j < 2; ++j) {
      int c = wc * 32 + j * 16 + lm;
      #pragma unroll
      for (int k = 0; k < 4; ++k) {
        int r = row0 + wr * 64 + i * 16 + lq * 4 + k;
        Cp[(size_t)r * ldc + c] = acc[i][j][k];
      }
    }
  }
}

// ---------------- sum K-split partials + bias -> BCm2 (stride 64) + Bp2 ----------------
__global__ __launch_bounds__(256) void prep_bc_sum(
    const float* __restrict__ parts,
    const float* __restrict__ bB, const float* __restrict__ bC,
    float* __restrict__ BCm2, float* __restrict__ Bp2) {
  int idx = blockIdx.x * 256 + threadIdx.x;   // M_SZ * 32
  int row = idx >> 5, c = idx & 31;
  float s = 0.f;
  #pragma unroll
  for (int kz = 0; kz < KZN; ++kz)
    s += parts[(size_t)kz * M_SZ * 64 + (size_t)row * 64 + c];
  s += (c & 1) ? bC[c >> 1] : bB[c >> 1];
  BCm2[(size_t)row * 64 + c] = s;
  if (!(c & 1))
    Bp2[(size_t)(row >> 1) * 32 + (c >> 1) * 2 + (row & 1)] = s;
}

// ---------------- selective scan: two-pass segmented, bitwise-exact, ZERO LDS ----------------
__device__ __forceinline__ float clampA(float a) {
  return fminf(fmaxf(a, -10.f), 2.f);
}

// ---- pass 1: boundary states, (d,s)-lane, deep register pipeline (r5) ----
__global__ __launch_bounds__(256, 1) void scan_pass1(
    const float* __restrict__ xc, const float* __restrict__ Bp2,
    const float* __restrict__ A_log, float* __restrict__ hseg) {
  const int b    = blockIdx.y;
  const int wave = threadIdx.x >> 6;
  const int lane = threadIdx.x & 63;
  const int dd   = lane >> 4, s = lane & 15;
  const int d    = blockIdx.x * 16 + wave * 4 + dd;

  const float A = -expf(clampA(A_log[d * DS + s]));
  float h = 0.f;

  const float* px = xc  + (size_t)b * L_SZ * DI + d;            // x: same addr across 16 s-lanes
  const float* pb = Bp2 + (size_t)b * (L_SZ / 2) * 32 + s * 2;  // paired B

  float  x0[SEG1], x1[SEG1];
  float2 b0[SEG1 / 2], b1[SEG1 / 2];

  // prologue: buffer 0
  #pragma unroll
  for (int j = 0; j < SEG1; ++j) x0[j] = px[j * DI];
  #pragma unroll
  for (int j = 0; j < SEG1 / 2; ++j) b0[j] = *(const float2*)(pb + j * 32);
  px += SEG1 * DI; pb += (SEG1 / 2) * 32;

  // 62 buffers of 32 steps = 1984 steps; boundary store every 2 buffers (64 steps)
  for (int w = 0; w < 60; w += 2) {
    #pragma unroll
    for (int j = 0; j < SEG1; ++j) x1[j] = px[j * DI];
    #pragma unroll
    for (int j = 0; j < SEG1 / 2; ++j) b1[j] = *(const float2*)(pb + j * 32);
    px += SEG1 * DI; pb += (SEG1 / 2) * 32;
    #pragma unroll
    for (int j = 0; j < SEG1; ++j) {
      float bj = (j & 1) ? b0[j >> 1].y : b0[j >> 1].x;
      h = __builtin_amdgcn_fmed3f(fmaf(h, A, x0[j] * bj), -100.f, 100.f);
    }
    #pragma unroll
    for (int j = 0; j < SEG1; ++j) x0[j] = px[j * DI];
    #pragma unroll
    for (int j = 0; j < SEG1 / 2; ++j) b0[j] = *(const float2*)(pb + j * 32);
    px += SEG1 * DI; pb += (SEG1 / 2) * 32;
    #pragma unroll
    for (int j = 0; j < SEG1; ++j) {
      float bj = (j & 1) ? b1[j >> 1].y : b1[j >> 1].x;
      h = __builtin_amdgcn_fmed3f(fmaf(h, A, x1[j] * bj), -100.f, 100.f);
    }
    hseg[(((size_t)b * (SEGS - 1) + (w >> 1)) * DI + d) * DS + s] = h;
  }
  // epilogue: buffers 60 (in buf0), 61 (load now); boundary 30
  #pragma unroll
  for (int j = 0; j < SEG1; ++j) x1[j] = px[j * DI];
  #pragma unroll
  for (int j = 0; j < SEG1 / 2; ++j) b1[j] = *(const float2*)(pb + j * 32);
  #pragma unroll
  for (int j = 0; j < SEG1; ++j) {
    float bj = (j & 1) ? b0[j >> 1].y : b0[j >> 1].x;
    h = __builtin_amdgcn_fmed3f(fmaf(h, A, x0[j] * bj), -100.f, 100.f);
  }
  #pragma unroll
  for (int j = 0; j < SEG1; ++j) {
    float bj = (j & 1) ? b1[j >> 1].y : b1[j >> 1].x;
    h = __builtin_amdgcn_fmed3f(fmaf(h, A, x1[j] * bj), -100.f, 100.f);
  }
  hseg[(((size_t)b * (SEGS - 1) + 30) * DI + d) * DS + s] = h;
}

// ---- pass 2: channel-major, h[16]/A[16] in registers, zero cross-lane (r4) ----
__global__ __launch_bounds__(256, 2) void scan_pass2(
    const float* __restrict__ xc, const float* __restrict__ BCm2,
    const unsigned short* __restrict__ zb,
    const float* __restrict__ A_log, const float* __restrict__ Dv,
    const float* __restrict__ hseg, unsigned short* __restrict__ yg) {
  const int b   = blockIdx.y >> 5;        // SEGS = 32
  const int seg = blockIdx.y & 31;
  const int d   = blockIdx.x * 256 + threadIdx.x;

  float A[16], h[16];
  #pragma unroll
  for (int q = 0; q < 4; ++q) {
    float4 al = *(const float4*)(A_log + d * DS + q * 4);
    A[q * 4 + 0] = -expf(clampA(al.x));
    A[q * 4 + 1] = -expf(clampA(al.y));
    A[q * 4 + 2] = -expf(clampA(al.z));
    A[q * 4 + 3] = -expf(clampA(al.w));
  }
  const float Dr = Dv[d];
  if (seg == 0) {
    #pragma unroll
    for (int s = 0; s < 16; ++s) h[s] = 0.f;
  } else {
    const float* hp = hseg + (((size_t)b * (SEGS - 1) + seg - 1) * DI + d) * DS;
    #pragma unroll
    for (int q = 0; q < 4; ++q) {
      float4 hv = *(const float4*)(hp + q * 4);
      h[q * 4 + 0] = hv.x; h[q * 4 + 1] = hv.y;
      h[q * 4 + 2] = hv.z; h[q * 4 + 3] = hv.w;
    }
  }

  const int rbase = b * L_SZ + seg * SEGLEN;
  const float*          px  = xc  + (size_t)rbase * DI + d;
  const unsigned short* pz  = zb  + (size_t)rbase * DI + d;
  unsigned short*       py  = yg  + (size_t)rbase * DI + d;
  const float*          pbc = BCm2 + (size_t)rbase * 64;

  #pragma unroll 2
  for (int t = 0; t < SEGLEN; ++t) {
    const float x = px[t * DI];
    const float* bc = pbc + t * 64;   // wave-uniform address
    float y = Dr * x;
    #pragma unroll
    for (int s = 0; s < 16; ++s) {
      h[s] = __builtin_amdgcn_fmed3f(fmaf(h[s], A[s], x * bc[s * 2]), -100.f, 100.f);
      y = fmaf(h[s], bc[s * 2 + 1], y);
    }
    y = __builtin_amdgcn_fmed3f(y, -100.f, 100.f);
    const float zf = frombf(pz[t * DI]);
    py[t * DI] = rne16(y * (1.f / (1.f + expf(-zf))));
  }
}

// ---------------- launch ----------------
// ws layout (bytes), peak 88.6 MB:
//   [0,        16777216)  yg bf16 (after conv; region was xi fp32 GEMM1 out)
//   [16777216, 25165824)  parts fp32 (gemm_bcf K-split partials, 8 MB; dead
//                          after prep_bc_sum) -- then hseg fp32 [16777216, 24903680)
//   [25165824, 26214400)  BCm2 fp32 stride-64 {B,C} (1 MB)
//   [26214400, 26476544)  Bp2 fp32 paired-B (256 KB)
//   [0,        33554432)  xi fp32 before conv (GEMM1 out, conv in)
//   [33554432, 50331648)  z bf16
//   [50331648, 83886080)  xc fp32 (conv out); BEFORE conv hosts xh/xl/WhT/WlT
//   [83886080, 84410368)  WbcT bf16 hi+lo (exact 512 KB, always-free old Bm/Cm slot)
//   [84410368, 88604672)  WoutT bf16
extern "C" void kernel_launch(void* const* d_in, const int* in_sizes, int n_in,
                              void* d_out, int out_size, void* d_ws, size_t ws_size,
                              hipStream_t stream) {
  const float* x      = (const float*)d_in[0];
  const float* W_in   = (const float*)d_in[1];
  const float* b_in   = (const float*)d_in[2];
  const float* W_conv = (const float*)d_in[3];
  const float* b_conv = (const float*)d_in[4];
  const float* A_log  = (const float*)d_in[5];
  const float* Dv     = (const float*)d_in[6];
  const float* W_B    = (const float*)d_in[7];
  const float* b_B    = (const float*)d_in[8];
  const float* W_C    = (const float*)d_in[9];
  const float* b_C    = (const float*)d_in[10];
  const float* W_out  = (const float*)d_in[11];
  const float* b_out  = (const float*)d_in[12];
  float* out = (float*)d_out;

  char* w = (char*)d_ws;
  float*          xi    = (float*)(w + 0);
  unsigned short* yg    = (unsigned short*)(w + 0);          // reuse after conv
  float*          parts = (float*)(w + 16777216);            // dead-xi zone
  float*          hseg  = (float*)(w + 16777216);            // after parts die
  float*          BCm2  = (float*)(w + 25165824);
  float*          Bp2   = (float*)(w + 26214400);
  unsigned short* zb    = (unsigned short*)(w + 33554432);
  float*          xc    = (float*)(w + 50331648);
  unsigned short* xh    = (unsigned short*)(w + 50331648);   // pre-conv phase
  unsigned short* xl    = (unsigned short*)(w + 58720256);
  unsigned short* WhT   = (unsigned short*)(w + 67108864);
  unsigned short* WlT   = (unsigned short*)(w + 75497472);
  unsigned short* WbcTh = (unsigned short*)(w + 83886080);
  unsigned short* WbcTl = (unsigned short*)(w + 84148224);
  unsigned short* WoT   = (unsigned short*)(w + 84410368);

  // 0a) x -> xh/xl
  convert_x<<<M_SZ * DM / 1024, 256, 0, stream>>>(x, xh, xl);
  // 0b) W_in (DM x N_XZ) -> WhT/WlT (N_XZ x DM)
  transpose_w<<<dim3(N_XZ / 64, DM / 64), 256, 0, stream>>>(W_in, DM, N_XZ, WhT, WlT);
  // 0c) W_out (DI x DM) -> WoT (DM x DI), hi only (post-scan path)
  transpose_w<<<dim3(DM / 64, DI / 64), 256, 0, stream>>>(W_out, DI, DM, WoT, nullptr);
  // 0d) W_B/W_C -> WbcT hi/lo (always-free 512KB slot)
  prep_wbc<<<64 * 2048 / 256, 256, 0, stream>>>(W_B, W_C, WbcTh, WbcTl);

  // 1a) xi = x @ W_in[:, :DI] + b_in[:DI]  -- bf16x3 (scan-sensitive), fp32 out
  gemm_t<128, true, false><<<dim3(DI / 128, M_SZ / 128), 256, 0, stream>>>(
      xh, xl, DM, WhT, WlT, DM, b_in, xi, nullptr, DI, DM);

  // 1b) z = x @ W_in[:, DI:] + b_in[DI:]  -- plain bf16 (gate path), bf16 out
  gemm_t<128, false, true><<<dim3(DI / 128, M_SZ / 128), 256, 0, stream>>>(
      xh, nullptr, DM, WhT + (size_t)DI * DM, nullptr, DM,
      b_in + DI, nullptr, zb, DI, DM);

  // 2) xc = silu(causal_dwconv(xi) + b_conv)
  conv_silu_kernel<<<M_SZ * DI / 256, 256, 0, stream>>>(xi, W_conv, b_conv, xc);

  // 3a) B/C projection partials via MFMA (K-split 8, full chip)
  gemm_bcf<<<dim3(KZN, M_SZ / 128), 256, 0, stream>>>(
      xc, DI, WbcTh, WbcTl, DI, parts, 64, DI / KZN);
  // 3b) sum partials + bias -> BCm2 (stride 64) + Bp2
  prep_bc_sum<<<M_SZ * 32 / 256, 256, 0, stream>>>(parts, b_B, b_C, BCm2, Bp2);

  // 4a) pass1: serial recurrence l=0..1983, deep register pipeline, 31 boundaries
  scan_pass1<<<dim3(DI / 16, B_SZ), 256, 0, stream>>>(xc, Bp2, A_log, hseg);

  // 4b) pass2: 32 parallel 64-step segments -> yg bf16 (bitwise == serial)
  scan_pass2<<<dim3(DI / 256, B_SZ * SEGS), 256, 0, stream>>>(
      xc, BCm2, zb, A_log, Dv, hseg, yg);

  // 5) out = yg @ W_out + b_out, pure bf16 MFMA (BN=64)
  gemm_t<64, false, false><<<dim3(DM / 64, M_SZ / 128), 256, 0, stream>>>(
      yg, nullptr, DI, WoT, nullptr, DI, b_out, out, nullptr, DM, DI);
}